// Round 12
// baseline (132.238 us; speedup 1.0000x reference)
//
#include <hip/hip_runtime.h>

// Problem constants (from setup_inputs): nframes=8, nloc=8192, nnei=128,
// nall=16384, ntypes=4, nspline=2000.
constexpr int NFRAMES = 8;
constexpr int NLOC    = 8192;
constexpr int NNEI    = 128;
constexpr int NALL    = 16384;
constexpr int NTYPES  = 4;
constexpr int NSPLINE = 2000;

// Opaque dataflow barrier: producer invisible to the optimizer, so no
// contraction/reassociation/refolding can touch the rounding chain.
#define FP_BAR(x) asm volatile("" : "+v"(x))

__global__ __launch_bounds__(256) void pack_kernel(
    const float* __restrict__ coord, const int* __restrict__ atype,
    float4* __restrict__ pack)
{
    int t = blockIdx.x * 256 + threadIdx.x;   // grid sized exactly
    float4 v;
    v.x = coord[3 * (size_t)t + 0];
    v.y = coord[3 * (size_t)t + 1];
    v.z = coord[3 * (size_t)t + 2];
    v.w = __int_as_float(atype[t]);
    pack[t] = v;
}

// VERIFIED ref chain (r11, absmax 3.8e-6 — DO NOT TOUCH):
//   ss = fma(dz,dz, fma(dx,dx, dy*dy))   [LLVM canonical contraction]
//   rr = CR f32 sqrt (sqrtf)
//   uu = rr * f32(1/hh)                  [= 200.0 exactly; rmin=0]
//   idx = trunc(uu); poly/sum in f64 (post-bin, ~1e-6 effect)
__device__ __forceinline__ double nb_energy(float4 c, bool valid,
                                            float xl, float yl, float zl,
                                            float rmin, float recip,
                                            const float* __restrict__ tabi)
{
    float dx = c.x - xl;  FP_BAR(dx);
    float dy = c.y - yl;  FP_BAR(dy);
    float dz = c.z - zl;  FP_BAR(dz);
    float my = dy * dy;                    FP_BAR(my);
    float t1 = __builtin_fmaf(dx, dx, my); FP_BAR(t1);   // canonical inner
    float ss = __builtin_fmaf(dz, dz, t1); FP_BAR(ss);
    float rr = sqrtf(ss);                  FP_BAR(rr);   // CR
    float num = rr - rmin;               FP_BAR(num);    // rmin=0: num==rr
    float uu  = num * recip;             FP_BAR(uu);     // recip-mul form
    int   idx = (int)uu;                 // trunc toward zero == astype(int32)
    double t  = (double)uu - (double)idx;                // exact (Sterbenz)
    int clip  = idx < 0 ? 0 : (idx > NSPLINE - 1 ? NSPLINE - 1 : idx);
    int tj    = __float_as_int(c.w);
    const float4 coef =
        *(const float4*)(tabi + (((size_t)tj * NSPLINE + clip) << 2));
    double e = (((double)coef.x * t + (double)coef.y) * t + (double)coef.z) * t
               + (double)coef.w;
    // rcut=6 < rmin+nspline*hh (=10), so rr>=6 is the only live cutoff
    bool zero = (!valid) | (idx > NSPLINE) | (rr >= 6.0f);
    return zero ? 0.0 : e;
}

// r12 perf change: 4 neighbors/lane (int4 nlist load) -> one wave covers TWO
// locs (lanes 0-31 -> loc 2w, lanes 32-63 -> loc 2w+1). Doubles outstanding
// L2 gathers per wave (r11 was 4.4 cyc/neighbor vs ~2 cyc TA floor; VALU 26%,
// HBM 6% -> gather-latency bound). Same per-neighbor math, f64 sum order
// change only (~1e-16).
__global__ __launch_bounds__(256) void pairtab_kernel(
    const float4* __restrict__ pack,
    const float*  __restrict__ tab,       // [NTYPES][NTYPES][NSPLINE][4]
    const float*  __restrict__ tab_info,  // [rmin, hh, nspline, ntypes]
    const int*    __restrict__ nlist,     // [NFRAMES][NLOC][NNEI] int32
    float*        __restrict__ out)       // [NFRAMES][NLOC]
{
    const int lane = threadIdx.x & 63;
    const int wid  = (blockIdx.x * 256 + threadIdx.x) >> 6;  // wave id = loc pair
    const int half = lane >> 5;                  // 0: loc 2w, 1: loc 2w+1
    const int gloc = 2 * wid + half;             // global loc index
    const int f = gloc >> 13;                    // / NLOC
    const int i = gloc & (NLOC - 1);

    const float rmin = tab_info[0];
    const float hh   = tab_info[1];
    // CR f32 reciprocal via f64 + single rounding (safe double rounding,
    // 53>=2*24+2) == f32 divide(1,hh) == exactly 200.0f for this data.
    float recip = (float)(1.0 / (double)hh);  FP_BAR(recip);

    const float4 pl = pack[(size_t)f * NALL + i];   // half-uniform, broadcast
    const float xl = pl.x, yl = pl.y, zl = pl.z;
    const int   ti = __float_as_int(pl.w);
    const float* tabi = tab + (size_t)ti * (NTYPES * NSPLINE * 4);

    // coalesced: lane reads 4 consecutive neighbor indices (16B/lane);
    // lane l covers neighbors 4l..4l+3 of the wave's 256-index window, which
    // is exactly rows {2w, 2w+1}: lanes 0-31 row A, 32-63 row B.
    const int4 jj = ((const int4*)(nlist + (size_t)wid * 256))[lane];
    const int j0 = jj.x, j1 = jj.y, j2 = jj.z, j3 = jj.w;
    const int mj0 = j0 < 0 ? 0 : j0;    // masked lanes gather atom 0
    const int mj1 = j1 < 0 ? 0 : j1;
    const int mj2 = j2 < 0 ? 0 : j2;
    const int mj3 = j3 < 0 ? 0 : j3;

    // issue all four pack gathers up front for MLP
    const size_t fb = (size_t)f * NALL;
    const float4 c0 = pack[fb + mj0];
    const float4 c1 = pack[fb + mj1];
    const float4 c2 = pack[fb + mj2];
    const float4 c3 = pack[fb + mj3];

    double esum = nb_energy(c0, j0 >= 0, xl, yl, zl, rmin, recip, tabi)
                + nb_energy(c1, j1 >= 0, xl, yl, zl, rmin, recip, tabi)
                + nb_energy(c2, j2 >= 0, xl, yl, zl, rmin, recip, tabi)
                + nb_energy(c3, j3 >= 0, xl, yl, zl, rmin, recip, tabi);

    // butterfly within each 32-lane half (xor offsets < 32 stay in-half)
#pragma unroll
    for (int off = 16; off >= 1; off >>= 1)
        esum += __shfl_xor(esum, off, 64);

    if ((lane & 31) == 0) out[gloc] = (float)(0.5 * esum);
}

extern "C" void kernel_launch(void* const* d_in, const int* in_sizes, int n_in,
                              void* d_out, int out_size, void* d_ws, size_t ws_size,
                              hipStream_t stream)
{
    const float* coord   = (const float*)d_in[0];   // (8,16384,3) f32
    const float* tab     = (const float*)d_in[1];   // (4,4,2000,4) f32
    const float* tabinfo = (const float*)d_in[2];   // (4,) f32
    const int*   atype   = (const int*)d_in[3];     // (8,16384) int32
    const int*   nlist   = (const int*)d_in[4];     // (8,8192,128) int32
    float* out  = (float*)d_out;                    // (8,8192,1) f32
    float4* pack = (float4*)d_ws;                   // 8*16384*16 = 2 MiB

    pack_kernel<<<(NFRAMES * NALL) / 256, 256, 0, stream>>>(coord, atype, pack);
    // one wave per 2 locs: 8*8192/2 = 32768 waves = 8192 blocks of 256
    pairtab_kernel<<<(NFRAMES * NLOC) / 8, 256, 0, stream>>>(pack, tab, tabinfo,
                                                             nlist, out);
}